// Round 1
// baseline (1086.834 us; speedup 1.0000x reference)
//
#include <hip/hip_runtime.h>
#include <hip/hip_bf16.h>

#define NE 8
#define HID 1024
#define INT_ 4096
#define NTOK 8192
#define CAP 2560

typedef short short8 __attribute__((ext_vector_type(8)));
typedef float floatx4 __attribute__((ext_vector_type(4)));

__device__ __forceinline__ unsigned short f2bf(float f) {
  union { float f; unsigned int u; } v; v.f = f;
  unsigned int u = v.u;
  return (unsigned short)((u + 0x7fffu + ((u >> 16) & 1u)) >> 16);
}

__device__ __forceinline__ void gl2lds16(const void* g, void* l) {
  __builtin_amdgcn_global_load_lds(
      (const __attribute__((address_space(1))) unsigned int*)g,
      (__attribute__((address_space(3))) unsigned int*)l, 16, 0, 0);
}

// ---------------- zero output ----------------
__global__ void zero_f4_kernel(float4* __restrict__ p) {
  p[(size_t)blockIdx.x * 256 + threadIdx.x] = make_float4(0.f, 0.f, 0.f, 0.f);
}

// ---------------- routing: cumsum position-in-expert ----------------
__global__ void routing_kernel(const int* __restrict__ eidx, const float* __restrict__ aff,
                               int* __restrict__ tfs, float* __restrict__ sw,
                               int* __restrict__ counts) {
  __shared__ unsigned long long masks[128];
  __shared__ int ccnt[128];
  int e = blockIdx.x;
  int tid = threadIdx.x;
  int wave = tid >> 6, lane = tid & 63;

  for (int ch = wave; ch < 128; ch += 4) {
    int t = ch * 64 + lane;
    int2 pr = ((const int2*)eidx)[t];
    bool chosen = (pr.x == e) || (pr.y == e);
    unsigned long long m = __ballot(chosen);
    if (lane == 0) { masks[ch] = m; ccnt[ch] = __popcll(m); }
  }
  __syncthreads();
  if (tid == 0) {
    int run = 0;
    for (int i = 0; i < 128; ++i) { int c = ccnt[i]; ccnt[i] = run; run += c; }
    counts[e] = run < CAP ? run : CAP;
  }
  __syncthreads();
  for (int ch = wave; ch < 128; ch += 4) {
    int t = ch * 64 + lane;
    unsigned long long m = masks[ch];
    if ((m >> lane) & 1ull) {
      int pos = ccnt[ch] + __popcll(m & ((2ull << lane) - 1ull)); // 1-indexed
      if (pos <= CAP) {
        int slot = e * CAP + pos - 1;
        tfs[slot] = t;
        int2 pr = ((const int2*)eidx)[t];
        int other = (pr.x == e) ? pr.y : pr.x;
        float a0 = aff[t * NE + e], a1 = aff[t * NE + other];
        sw[slot] = a0 / (a0 + a1);
      }
    }
  }
}

// ---------------- transpose + fp32->bf16 convert: in [z][R][Cc] -> out [z][Cc][R] ----------------
__global__ void transpose_cvt_kernel(const float* __restrict__ in, unsigned short* __restrict__ out,
                                     int R, int Cc) {
  __shared__ float tile[64][33];
  int z = blockIdx.z;
  int r0 = blockIdx.y * 64, c0 = blockIdx.x * 32;
  const float* inp = in + (size_t)z * R * Cc;
  unsigned short* outp = out + (size_t)z * R * Cc;
  int tx = threadIdx.x, ty = threadIdx.y;
#pragma unroll
  for (int j = 0; j < 8; ++j) {
    int r = ty + j * 8;
    tile[r][tx] = inp[(size_t)(r0 + r) * Cc + c0 + tx];
  }
  __syncthreads();
#pragma unroll
  for (int j = 0; j < 4; ++j) {
    int c = ty + j * 8;
    ushort2 p;
    p.x = f2bf(tile[2 * tx][c]);
    p.y = f2bf(tile[2 * tx + 1][c]);
    *(ushort2*)(outp + (size_t)(c0 + c) * R + r0 + 2 * tx) = p;
  }
}

// ---------------- dispatch: gather tokens into (E,C,H) bf16 buffer ----------------
__global__ void dispatch_kernel(const float* __restrict__ x, const int* __restrict__ tfs,
                                const int* __restrict__ counts, unsigned short* __restrict__ ebuf) {
  int slot = blockIdx.x;
  int e = slot / CAP, c = slot - e * CAP;
  bool valid = c < counts[e];
  int t = valid ? tfs[slot] : 0;
  const float4* src = (const float4*)(x + (size_t)t * HID);
  ushort4* dst = (ushort4*)(ebuf + (size_t)slot * HID);
#pragma unroll
  for (int j = 0; j < 2; ++j) {
    int i = threadIdx.x + j * 128;
    ushort4 p;
    if (valid) {
      float4 v = src[i];
      p.x = f2bf(v.x); p.y = f2bf(v.y); p.z = f2bf(v.z); p.w = f2bf(v.w);
    } else {
      p.x = p.y = p.z = p.w = 0;
    }
    dst[i] = p;
  }
}

// ---------------- GEMM1: ebuf(E,C,H) x wgu_t(E,2I,H) -> silu(gate)*up*w -> inter(E,C,I) bf16 ----------------
__global__ void gemm1_kernel(const unsigned short* __restrict__ ebuf,
                             const unsigned short* __restrict__ wgu,
                             const float* __restrict__ sw,
                             const int* __restrict__ counts,
                             unsigned short* __restrict__ inter) {
  int e = blockIdx.z;
  int c0 = blockIdx.y * 128;
  int f0 = blockIdx.x * 64;
  int cnt = counts[e];
  if (c0 >= cnt) return;

  __shared__ alignas(16) unsigned short smem[16384]; // 32 KB
  unsigned short* sA = smem;          // [128][64]
  unsigned short* sBg = smem + 8192;  // [64][64]
  unsigned short* sBu = smem + 12288; // [64][64]

  int tid = threadIdx.x;
  int wave = tid >> 6, lane = tid & 63;
  int wm = (wave & 1) * 64;
  int isUp = wave >> 1;
  int lrow = lane >> 3, lch = lane & 7;
  int quad = lane >> 4, rl = lane & 15;

  const unsigned short* Ab = ebuf + ((size_t)e * CAP + c0) * HID;
  const unsigned short* Bb = wgu + ((size_t)e * 2 * INT_ + isUp * INT_ + f0) * HID;
  unsigned short* sB = isUp ? sBu : sBg;

  floatx4 acc[4][4];
#pragma unroll
  for (int i = 0; i < 4; ++i)
#pragma unroll
    for (int j = 0; j < 4; ++j) acc[i][j] = (floatx4){0.f, 0.f, 0.f, 0.f};

  for (int kk = 0; kk < HID; kk += 64) {
    __syncthreads();
#pragma unroll
    for (int i = 0; i < 4; ++i) {
      int r = wave * 32 + i * 8 + lrow;
      int gk = kk + ((lch ^ (r & 7)) << 3);
      gl2lds16(Ab + (size_t)r * HID + gk, sA + (wave * 32 + i * 8) * 64);
    }
#pragma unroll
    for (int i = 0; i < 4; ++i) {
      int r = (wave & 1) * 32 + i * 8 + lrow;
      int gk = kk + ((lch ^ (r & 7)) << 3);
      gl2lds16(Bb + (size_t)r * HID + gk, sB + ((wave & 1) * 32 + i * 8) * 64);
    }
    __syncthreads();
#pragma unroll
    for (int ks = 0; ks < 2; ++ks) {
      short8 a[4], b[4];
#pragma unroll
      for (int mi = 0; mi < 4; ++mi) {
        int r = wm + mi * 16 + rl;
        int pc = (ks * 4 + quad) ^ (r & 7);
        a[mi] = *(const short8*)(sA + r * 64 + pc * 8);
      }
#pragma unroll
      for (int ni = 0; ni < 4; ++ni) {
        int r = ni * 16 + rl;
        int pc = (ks * 4 + quad) ^ (r & 7);
        b[ni] = *(const short8*)(sB + r * 64 + pc * 8);
      }
#pragma unroll
      for (int mi = 0; mi < 4; ++mi)
#pragma unroll
        for (int ni = 0; ni < 4; ++ni)
          acc[mi][ni] = __builtin_amdgcn_mfma_f32_16x16x32_bf16(a[mi], b[ni], acc[mi][ni], 0, 0, 0);
    }
  }

  __syncthreads();
  float* gsh = (float*)smem; // [128][64] fp32 = 32 KB, reuse tiles
  if (!isUp) {
#pragma unroll
    for (int mi = 0; mi < 4; ++mi)
#pragma unroll
      for (int ni = 0; ni < 4; ++ni)
#pragma unroll
        for (int r = 0; r < 4; ++r) {
          int row = wm + mi * 16 + quad * 4 + r;
          int col = ni * 16 + rl;
          gsh[row * 64 + col] = acc[mi][ni][r];
        }
  }
  __syncthreads();
  if (isUp) {
#pragma unroll
    for (int mi = 0; mi < 4; ++mi) {
#pragma unroll
      for (int r = 0; r < 4; ++r) {
        int row = wm + mi * 16 + quad * 4 + r;
        float w = sw[(size_t)e * CAP + c0 + row];
#pragma unroll
        for (int ni = 0; ni < 4; ++ni) {
          int col = ni * 16 + rl;
          float g = gsh[row * 64 + col];
          float u = acc[mi][ni][r];
          float s = g / (1.f + __expf(-g));
          inter[((size_t)e * CAP + c0 + row) * INT_ + f0 + col] = f2bf(s * u * w);
        }
      }
    }
  }
}

// ---------------- GEMM2: inter(E,C,I) x wd_t(E,H,I) -> atomicAdd combine into out(T,H) ----------------
__global__ void gemm2_kernel(const unsigned short* __restrict__ inter,
                             const unsigned short* __restrict__ wd,
                             const int* __restrict__ tfs,
                             const int* __restrict__ counts,
                             float* __restrict__ out) {
  int e = blockIdx.z;
  int c0 = blockIdx.y * 128;
  int h0 = blockIdx.x * 128;
  int cnt = counts[e];
  if (c0 >= cnt) return;

  __shared__ alignas(16) unsigned short smem[16384]; // 32 KB
  unsigned short* sA = smem;        // [128][64]
  unsigned short* sB = smem + 8192; // [128][64]

  int tid = threadIdx.x;
  int wave = tid >> 6, lane = tid & 63;
  int wm = (wave & 1) * 64, wn = (wave >> 1) * 64;
  int lrow = lane >> 3, lch = lane & 7;
  int quad = lane >> 4, rl = lane & 15;

  const unsigned short* Ab = inter + ((size_t)e * CAP + c0) * INT_;
  const unsigned short* Bb = wd + ((size_t)e * HID + h0) * INT_;

  floatx4 acc[4][4];
#pragma unroll
  for (int i = 0; i < 4; ++i)
#pragma unroll
    for (int j = 0; j < 4; ++j) acc[i][j] = (floatx4){0.f, 0.f, 0.f, 0.f};

  for (int kk = 0; kk < INT_; kk += 64) {
    __syncthreads();
#pragma unroll
    for (int i = 0; i < 4; ++i) {
      int r = wave * 32 + i * 8 + lrow;
      int gk = kk + ((lch ^ (r & 7)) << 3);
      gl2lds16(Ab + (size_t)r * INT_ + gk, sA + (wave * 32 + i * 8) * 64);
      gl2lds16(Bb + (size_t)r * INT_ + gk, sB + (wave * 32 + i * 8) * 64);
    }
    __syncthreads();
#pragma unroll
    for (int ks = 0; ks < 2; ++ks) {
      short8 a[4], b[4];
#pragma unroll
      for (int mi = 0; mi < 4; ++mi) {
        int r = wm + mi * 16 + rl;
        int pc = (ks * 4 + quad) ^ (r & 7);
        a[mi] = *(const short8*)(sA + r * 64 + pc * 8);
      }
#pragma unroll
      for (int ni = 0; ni < 4; ++ni) {
        int r = wn + ni * 16 + rl;
        int pc = (ks * 4 + quad) ^ (r & 7);
        b[ni] = *(const short8*)(sB + r * 64 + pc * 8);
      }
#pragma unroll
      for (int mi = 0; mi < 4; ++mi)
#pragma unroll
        for (int ni = 0; ni < 4; ++ni)
          acc[mi][ni] = __builtin_amdgcn_mfma_f32_16x16x32_bf16(a[mi], b[ni], acc[mi][ni], 0, 0, 0);
    }
  }

#pragma unroll
  for (int mi = 0; mi < 4; ++mi) {
#pragma unroll
    for (int r = 0; r < 4; ++r) {
      int row = wm + mi * 16 + quad * 4 + r;
      int gr = c0 + row;
      if (gr < cnt) {
        int t = tfs[(size_t)e * CAP + gr];
        float* op = out + (size_t)t * HID + h0;
#pragma unroll
        for (int ni = 0; ni < 4; ++ni) atomicAdd(op + wn + ni * 16 + rl, acc[mi][ni][r]);
      }
    }
  }
}

extern "C" void kernel_launch(void* const* d_in, const int* in_sizes, int n_in,
                              void* d_out, int out_size, void* d_ws, size_t ws_size,
                              hipStream_t stream) {
  const float* x = (const float*)d_in[0];        // (8192, 1024)
  const float* aff = (const float*)d_in[1];      // (8192, 8)
  const int* eidx = (const int*)d_in[2];         // (8192, 2)
  const float* wgu_f = (const float*)d_in[3];    // (8, 1024, 8192)
  const float* wd_f = (const float*)d_in[4];     // (8, 4096, 1024)
  float* out = (float*)d_out;                    // (8192, 1024)

  char* ws = (char*)d_ws;
  int* tfs = (int*)(ws + 0);                           // int[E*C]      81920 B
  float* sw = (float*)(ws + 81920);                    // float[E*C]    81920 B
  int* counts = (int*)(ws + 163840);                   // int[E]
  unsigned short* ebuf = (unsigned short*)(ws + 262144);      // bf16[8][2560][1024]
  unsigned short* wgu = (unsigned short*)(ws + 42205184);     // bf16[8][8192][1024]
  unsigned short* wd = (unsigned short*)(ws + 176422912);     // bf16[8][1024][4096]
  unsigned short* inter = (unsigned short*)(ws + 243531776);  // bf16[8][2560][4096]

  zero_f4_kernel<<<8192, 256, 0, stream>>>((float4*)out);
  routing_kernel<<<NE, 256, 0, stream>>>(eidx, aff, tfs, sw, counts);
  transpose_cvt_kernel<<<dim3(256, 16, NE), dim3(32, 8), 0, stream>>>(wgu_f, wgu, 1024, 8192);
  transpose_cvt_kernel<<<dim3(32, 64, NE), dim3(32, 8), 0, stream>>>(wd_f, wd, 4096, 1024);
  dispatch_kernel<<<NE * CAP, 128, 0, stream>>>(x, tfs, counts, ebuf);
  gemm1_kernel<<<dim3(64, 20, NE), 256, 0, stream>>>(ebuf, wgu, sw, counts, inter);
  gemm2_kernel<<<dim3(8, 20, NE), 256, 0, stream>>>(inter, wd, tfs, counts, out);
}

// Round 3
// 1037.139 us; speedup vs baseline: 1.0479x; 1.0479x over previous
//
#include <hip/hip_runtime.h>
#include <hip/hip_bf16.h>

#define NE 8
#define HID 1024
#define INT_ 4096
#define NTOK 8192
#define CAP 2560

typedef short short8 __attribute__((ext_vector_type(8)));
typedef float floatx4 __attribute__((ext_vector_type(4)));

__device__ __forceinline__ unsigned short f2bf(float f) {
  union { float f; unsigned int u; } v; v.f = f;
  unsigned int u = v.u;
  return (unsigned short)((u + 0x7fffu + ((u >> 16) & 1u)) >> 16);
}

__device__ __forceinline__ void gl2lds16(const void* g, void* l) {
  __builtin_amdgcn_global_load_lds(
      (const __attribute__((address_space(1))) unsigned int*)g,
      (__attribute__((address_space(3))) unsigned int*)l, 16, 0, 0);
}

// ---------------- routing: cumsum position-in-expert ----------------
__global__ void routing_kernel(const int* __restrict__ eidx,
                               int* __restrict__ tfs,
                               int* __restrict__ counts, int* __restrict__ slots) {
  __shared__ unsigned long long masks[128];
  __shared__ int ccnt[128];
  int e = blockIdx.x;
  int tid = threadIdx.x;
  int wave = tid >> 6, lane = tid & 63;

  for (int ch = wave; ch < 128; ch += 4) {
    int t = ch * 64 + lane;
    int2 pr = ((const int2*)eidx)[t];
    bool chosen = (pr.x == e) || (pr.y == e);
    unsigned long long m = __ballot(chosen);
    if (lane == 0) { masks[ch] = m; ccnt[ch] = __popcll(m); }
  }
  __syncthreads();
  if (tid == 0) {
    int run = 0;
    for (int i = 0; i < 128; ++i) { int c = ccnt[i]; ccnt[i] = run; run += c; }
    counts[e] = run < CAP ? run : CAP;
  }
  __syncthreads();
  for (int ch = wave; ch < 128; ch += 4) {
    int t = ch * 64 + lane;
    unsigned long long m = masks[ch];
    if ((m >> lane) & 1ull) {
      int pos = ccnt[ch] + __popcll(m & ((2ull << lane) - 1ull)); // 1-indexed
      int2 pr = ((const int2*)eidx)[t];
      int kk = (pr.x == e) ? 0 : 1;
      if (pos <= CAP) {
        int slot = e * CAP + pos - 1;
        tfs[slot] = t;
        slots[2 * t + kk] = slot;
      } else {
        slots[2 * t + kk] = -1;
      }
    }
  }
}

// ---------------- transpose + fp32->bf16: in [z][R][Cc] -> out [z][Cc][R] ----------------
__global__ void transpose_cvt_kernel(const float* __restrict__ in, unsigned short* __restrict__ out,
                                     int R, int Cc) {
  __shared__ unsigned short tile[64 * 66];
  int z = blockIdx.z;
  int r0 = blockIdx.y * 64, c0 = blockIdx.x * 64;
  const float* inp = in + (size_t)z * R * Cc;
  unsigned short* outp = out + (size_t)z * R * Cc;
  int tx = threadIdx.x & 15, ty = threadIdx.x >> 4;
#pragma unroll
  for (int j = 0; j < 4; ++j) {
    int r = ty + j * 16;
    float4 v = *(const float4*)(inp + (size_t)(r0 + r) * Cc + c0 + 4 * tx);
    tile[r * 66 + 4 * tx + 0] = f2bf(v.x);
    tile[r * 66 + 4 * tx + 1] = f2bf(v.y);
    tile[r * 66 + 4 * tx + 2] = f2bf(v.z);
    tile[r * 66 + 4 * tx + 3] = f2bf(v.w);
  }
  __syncthreads();
#pragma unroll
  for (int j = 0; j < 4; ++j) {
    int c = ty + j * 16;
    ushort4 p;
    p.x = tile[(4 * tx + 0) * 66 + c];
    p.y = tile[(4 * tx + 1) * 66 + c];
    p.z = tile[(4 * tx + 2) * 66 + c];
    p.w = tile[(4 * tx + 3) * 66 + c];
    *(ushort4*)(outp + (size_t)(c0 + c) * R + r0 + 4 * tx) = p;
  }
}

// ---------------- dispatch: gather tokens into (E,C,H) bf16 buffer ----------------
__global__ void dispatch_kernel(const float* __restrict__ x, const int* __restrict__ tfs,
                                const int* __restrict__ counts, unsigned short* __restrict__ ebuf) {
  int slot = blockIdx.x;
  int e = slot / CAP, c = slot - e * CAP;
  bool valid = c < counts[e];
  int t = valid ? tfs[slot] : 0;
  const float4* src = (const float4*)(x + (size_t)t * HID);
  ushort4* dst = (ushort4*)(ebuf + (size_t)slot * HID);
#pragma unroll
  for (int j = 0; j < 2; ++j) {
    int i = threadIdx.x + j * 128;
    ushort4 p;
    if (valid) {
      float4 v = src[i];
      p.x = f2bf(v.x); p.y = f2bf(v.y); p.z = f2bf(v.z); p.w = f2bf(v.w);
    } else {
      p.x = p.y = p.z = p.w = 0;
    }
    dst[i] = p;
  }
}

// ---------------- GEMM1: ebuf(E,C,H) x wgu_t(E,2I,H) -> silu(gate)*up -> inter(E,C,I) bf16 ----------------
__global__ void gemm1_kernel(const unsigned short* __restrict__ ebuf,
                             const unsigned short* __restrict__ wgu,
                             const int* __restrict__ counts,
                             unsigned short* __restrict__ inter) {
  int e = blockIdx.z;
  int c0 = blockIdx.y * 128;
  int f0 = blockIdx.x * 64;
  int cnt = counts[e];
  if (c0 >= cnt) return;

  __shared__ alignas(16) unsigned short smem[16384]; // 32 KB
  unsigned short* sA = smem;          // [128][64]
  unsigned short* sBg = smem + 8192;  // [64][64]
  unsigned short* sBu = smem + 12288; // [64][64]

  int tid = threadIdx.x;
  int wave = tid >> 6, lane = tid & 63;
  int wm = (wave & 1) * 64;
  int isUp = wave >> 1;
  int lrow = lane >> 3, lch = lane & 7;
  int quad = lane >> 4, rl = lane & 15;

  const unsigned short* Ab = ebuf + ((size_t)e * CAP + c0) * HID;
  const unsigned short* Bb = wgu + ((size_t)e * 2 * INT_ + isUp * INT_ + f0) * HID;
  unsigned short* sB = isUp ? sBu : sBg;

  floatx4 acc[4][4];
#pragma unroll
  for (int i = 0; i < 4; ++i)
#pragma unroll
    for (int j = 0; j < 4; ++j) acc[i][j] = (floatx4){0.f, 0.f, 0.f, 0.f};

  for (int kk = 0; kk < HID; kk += 64) {
    __syncthreads();
#pragma unroll
    for (int i = 0; i < 4; ++i) {
      int r = wave * 32 + i * 8 + lrow;
      int gk = kk + ((lch ^ (r & 7)) << 3);
      gl2lds16(Ab + (size_t)r * HID + gk, sA + (wave * 32 + i * 8) * 64);
    }
#pragma unroll
    for (int i = 0; i < 4; ++i) {
      int r = (wave & 1) * 32 + i * 8 + lrow;
      int gk = kk + ((lch ^ (r & 7)) << 3);
      gl2lds16(Bb + (size_t)r * HID + gk, sB + ((wave & 1) * 32 + i * 8) * 64);
    }
    __syncthreads();
#pragma unroll
    for (int ks = 0; ks < 2; ++ks) {
      short8 a[4], b[4];
#pragma unroll
      for (int mi = 0; mi < 4; ++mi) {
        int r = wm + mi * 16 + rl;
        int pc = (ks * 4 + quad) ^ (r & 7);
        a[mi] = *(const short8*)(sA + r * 64 + pc * 8);
      }
#pragma unroll
      for (int ni = 0; ni < 4; ++ni) {
        int r = ni * 16 + rl;
        int pc = (ks * 4 + quad) ^ (r & 7);
        b[ni] = *(const short8*)(sB + r * 64 + pc * 8);
      }
#pragma unroll
      for (int mi = 0; mi < 4; ++mi)
#pragma unroll
        for (int ni = 0; ni < 4; ++ni)
          acc[mi][ni] = __builtin_amdgcn_mfma_f32_16x16x32_bf16(a[mi], b[ni], acc[mi][ni], 0, 0, 0);
    }
  }

  __syncthreads();
  float* gsh = (float*)smem; // [128][64] fp32 = 32 KB, reuse tiles
  if (!isUp) {
#pragma unroll
    for (int mi = 0; mi < 4; ++mi)
#pragma unroll
      for (int ni = 0; ni < 4; ++ni)
#pragma unroll
        for (int r = 0; r < 4; ++r) {
          int row = wm + mi * 16 + quad * 4 + r;
          int col = ni * 16 + rl;
          gsh[row * 64 + col] = acc[mi][ni][r];
        }
  }
  __syncthreads();
  if (isUp) {
#pragma unroll
    for (int mi = 0; mi < 4; ++mi) {
#pragma unroll
      for (int r = 0; r < 4; ++r) {
        int row = wm + mi * 16 + quad * 4 + r;
#pragma unroll
        for (int ni = 0; ni < 4; ++ni) {
          int col = ni * 16 + rl;
          float g = gsh[row * 64 + col];
          float u = acc[mi][ni][r];
          float s = g / (1.f + __expf(-g));
          inter[((size_t)e * CAP + c0 + row) * INT_ + f0 + col] = f2bf(s * u);
        }
      }
    }
  }
}

// ---------------- GEMM2: inter(E,C,I) x wd_t(E,H,I) -> eout(E,C,H) fp32 ----------------
__global__ void gemm2_kernel(const unsigned short* __restrict__ inter,
                             const unsigned short* __restrict__ wd,
                             const int* __restrict__ counts,
                             float* __restrict__ eout) {
  int e = blockIdx.z;
  int c0 = blockIdx.y * 128;
  int h0 = blockIdx.x * 128;
  int cnt = counts[e];
  if (c0 >= cnt) return;

  __shared__ alignas(16) unsigned short smem[16384]; // 32 KB
  unsigned short* sA = smem;        // [128][64]
  unsigned short* sB = smem + 8192; // [128][64]

  int tid = threadIdx.x;
  int wave = tid >> 6, lane = tid & 63;
  int wm = (wave & 1) * 64, wn = (wave >> 1) * 64;
  int lrow = lane >> 3, lch = lane & 7;
  int quad = lane >> 4, rl = lane & 15;

  const unsigned short* Ab = inter + ((size_t)e * CAP + c0) * INT_;
  const unsigned short* Bb = wd + ((size_t)e * HID + h0) * INT_;

  floatx4 acc[4][4];
#pragma unroll
  for (int i = 0; i < 4; ++i)
#pragma unroll
    for (int j = 0; j < 4; ++j) acc[i][j] = (floatx4){0.f, 0.f, 0.f, 0.f};

  for (int kk = 0; kk < INT_; kk += 64) {
    __syncthreads();
#pragma unroll
    for (int i = 0; i < 4; ++i) {
      int r = wave * 32 + i * 8 + lrow;
      int gk = kk + ((lch ^ (r & 7)) << 3);
      gl2lds16(Ab + (size_t)r * INT_ + gk, sA + (wave * 32 + i * 8) * 64);
      gl2lds16(Bb + (size_t)r * INT_ + gk, sB + (wave * 32 + i * 8) * 64);
    }
    __syncthreads();
#pragma unroll
    for (int ks = 0; ks < 2; ++ks) {
      short8 a[4], b[4];
#pragma unroll
      for (int mi = 0; mi < 4; ++mi) {
        int r = wm + mi * 16 + rl;
        int pc = (ks * 4 + quad) ^ (r & 7);
        a[mi] = *(const short8*)(sA + r * 64 + pc * 8);
      }
#pragma unroll
      for (int ni = 0; ni < 4; ++ni) {
        int r = wn + ni * 16 + rl;
        int pc = (ks * 4 + quad) ^ (r & 7);
        b[ni] = *(const short8*)(sB + r * 64 + pc * 8);
      }
#pragma unroll
      for (int mi = 0; mi < 4; ++mi)
#pragma unroll
        for (int ni = 0; ni < 4; ++ni)
          acc[mi][ni] = __builtin_amdgcn_mfma_f32_16x16x32_bf16(a[mi], b[ni], acc[mi][ni], 0, 0, 0);
    }
  }

#pragma unroll
  for (int mi = 0; mi < 4; ++mi) {
#pragma unroll
    for (int r = 0; r < 4; ++r) {
      int row = wm + mi * 16 + quad * 4 + r;
      float* op = eout + ((size_t)e * CAP + c0 + row) * HID + h0;
#pragma unroll
      for (int ni = 0; ni < 4; ++ni) op[wn + ni * 16 + rl] = acc[mi][ni][r];
    }
  }
}

// ---------------- combine: out[t] = sum_k w_k * eout[slot_k] ----------------
__global__ void combine_kernel(const float4* __restrict__ eout, const int* __restrict__ slots,
                               const float* __restrict__ aff, const int* __restrict__ eidx,
                               float4* __restrict__ out) {
  int t = blockIdx.x;
  int i = threadIdx.x;
  int s0 = slots[2 * t], s1 = slots[2 * t + 1];
  int e0 = eidx[2 * t], e1 = eidx[2 * t + 1];
  float a0 = aff[t * NE + e0], a1 = aff[t * NE + e1];
  float inv = 1.f / (a0 + a1);
  float w0 = (s0 >= 0) ? a0 * inv : 0.f;
  float w1 = (s1 >= 0) ? a1 * inv : 0.f;
  int p0 = (s0 >= 0) ? s0 : 0;
  int p1 = (s1 >= 0) ? s1 : 0;
  float4 v0 = eout[(size_t)p0 * 256 + i];
  float4 v1 = eout[(size_t)p1 * 256 + i];
  float4 r;
  r.x = w0 * v0.x + w1 * v1.x;
  r.y = w0 * v0.y + w1 * v1.y;
  r.z = w0 * v0.z + w1 * v1.z;
  r.w = w0 * v0.w + w1 * v1.w;
  out[(size_t)t * 256 + i] = r;
}

extern "C" void kernel_launch(void* const* d_in, const int* in_sizes, int n_in,
                              void* d_out, int out_size, void* d_ws, size_t ws_size,
                              hipStream_t stream) {
  const float* x = (const float*)d_in[0];        // (8192, 1024)
  const float* aff = (const float*)d_in[1];      // (8192, 8)
  const int* eidx = (const int*)d_in[2];         // (8192, 2)
  const float* wgu_f = (const float*)d_in[3];    // (8, 1024, 8192)
  const float* wd_f = (const float*)d_in[4];     // (8, 4096, 1024)
  float* out = (float*)d_out;                    // (8192, 1024)

  char* ws = (char*)d_ws;
  int* tfs = (int*)(ws + 0);                           // int[E*C]      81920 B
  int* counts = (int*)(ws + 163840);                   // int[8]
  int* slots = (int*)(ws + 196608);                    // int[T*2]      65536 B
  unsigned short* ebuf = (unsigned short*)(ws + 262144);      // bf16[8][2560][1024]  ends 42205184
  unsigned short* wgu = (unsigned short*)(ws + 42205184);     // bf16[8][8192][1024]  ends 176422912
  unsigned short* wd = (unsigned short*)(ws + 176422912);     // bf16[8][1024][4096]  ends 243531776
  unsigned short* inter = (unsigned short*)(ws + 243531776);  // bf16[8][2560][4096]  ends 411303936
  // eout aliases wgu's region (wgu dead after gemm1): fp32[8][2560][1024] = 83886080 B < 134217728 B
  float* eout = (float*)(ws + 42205184);

  routing_kernel<<<NE, 256, 0, stream>>>(eidx, tfs, counts, slots);
  transpose_cvt_kernel<<<dim3(128, 16, NE), 256, 0, stream>>>(wgu_f, wgu, 1024, 8192);
  transpose_cvt_kernel<<<dim3(16, 64, NE), 256, 0, stream>>>(wd_f, wd, 4096, 1024);
  dispatch_kernel<<<NE * CAP, 128, 0, stream>>>(x, tfs, counts, ebuf);
  gemm1_kernel<<<dim3(64, 20, NE), 256, 0, stream>>>(ebuf, wgu, counts, inter);
  gemm2_kernel<<<dim3(8, 20, NE), 256, 0, stream>>>(inter, wd, counts, eout);
  combine_kernel<<<NTOK, 256, 0, stream>>>((const float4*)eout, slots, aff, eidx, (float4*)out);
}